// Round 1
// baseline (150.363 us; speedup 1.0000x reference)
//
#include <hip/hip_runtime.h>
#include <hip/hip_bf16.h>
#include <math.h>

#define D_DIM   1024
#define BS      80      // B * STEP
#define BATCH   16
#define STEPS   5
#define ALPHA   0.01f
#define BN_EPS  1e-5f
#define L2_EPS  1e-12f

// ---------------------------------------------------------------------------
// K1: closed-form fast-weight readout.
//   q[n,i] = ALPHA * sum_{s=0..t} c_s * x_k[s][i] * prod_{r=s+1..t}(1 - ALPHA*x_k[r][i]^2)
// where t = n>>4 (mem is step-major: step t, batch bb = n&15),
//       x_k[s] = x[bb*STEPS + s]  (keys, batch-major rows of x),
//       v      = x[n]             (query row, the reference's index mismatch),
//       c_s    = dot(x_k[s], v).
// One block per output row n (80 blocks, 256 threads).
// ---------------------------------------------------------------------------
__global__ __launch_bounds__(256) void k1_q(const float* __restrict__ x,
                                            float* __restrict__ q) {
    const int n   = blockIdx.x;
    const int tid = threadIdx.x;
    const int t   = n >> 4;    // 0..4 -> steps used = t+1
    const int bb  = n & 15;

    const float* __restrict__ v = x + (size_t)n * D_DIM;

    // partial dot products for all 5 keys (rows beyond t are valid memory; unused)
    float p[STEPS] = {0.f, 0.f, 0.f, 0.f, 0.f};
    for (int i = tid; i < D_DIM; i += 256) {
        const float vi = v[i];
#pragma unroll
        for (int s = 0; s < STEPS; ++s) {
            p[s] += x[(size_t)(bb * STEPS + s) * D_DIM + i] * vi;
        }
    }

    __shared__ float c[STEPS];
    __shared__ float sred[4];
#pragma unroll
    for (int s = 0; s < STEPS; ++s) {
        float r = p[s];
#pragma unroll
        for (int off = 32; off > 0; off >>= 1) r += __shfl_down(r, off, 64);
        if ((tid & 63) == 0) sred[tid >> 6] = r;
        __syncthreads();
        if (tid == 0) c[s] = sred[0] + sred[1] + sred[2] + sred[3];
        __syncthreads();
    }

    // per-element decayed recurrence
    for (int i = tid; i < D_DIM; i += 256) {
        float acc = 0.f;
        for (int s = 0; s <= t; ++s) {
            const float xs = x[(size_t)(bb * STEPS + s) * D_DIM + i];
            acc = acc * (1.f - ALPHA * xs * xs) + c[s] * xs;
        }
        q[(size_t)n * D_DIM + i] = ALPHA * acc;
    }
}

// ---------------------------------------------------------------------------
// K2: y = q @ W^T + b.  One thread per output element (80*1024 = 81920).
// Lane group shares q[n] (broadcast load); each thread streams its W row
// with float4 loads (line-reusing). W (4MB) is L2/L3 resident.
// ---------------------------------------------------------------------------
__global__ __launch_bounds__(256) void k2_gemm(const float* __restrict__ q,
                                               const float* __restrict__ W,
                                               const float* __restrict__ bvec,
                                               float* __restrict__ y) {
    const int gid = blockIdx.x * 256 + threadIdx.x;
    const int n = gid >> 10;
    const int j = gid & 1023;

    const float4* __restrict__ qr = (const float4*)(q + (size_t)n * D_DIM);
    const float4* __restrict__ wr = (const float4*)(W + (size_t)j * D_DIM);

    float acc = 0.f;
#pragma unroll 4
    for (int i = 0; i < D_DIM / 4; ++i) {
        const float4 a = qr[i];
        const float4 w = wr[i];
        acc += a.x * w.x + a.y * w.y + a.z * w.z + a.w * w.w;
    }
    y[gid] = acc + bvec[j];
}

// ---------------------------------------------------------------------------
// K3: column-wise BatchNorm statistics over the 80-row batch (biased var).
// One thread per column; coalesced strided reads.
// ---------------------------------------------------------------------------
__global__ __launch_bounds__(256) void k3_stats(const float* __restrict__ y,
                                                float* __restrict__ mu,
                                                float* __restrict__ istd) {
    const int j = blockIdx.x * 256 + threadIdx.x;
    float s = 0.f;
    for (int n = 0; n < BS; ++n) s += y[(size_t)n * D_DIM + j];
    const float m = s * (1.f / (float)BS);
    float s2 = 0.f;
    for (int n = 0; n < BS; ++n) {
        const float d = y[(size_t)n * D_DIM + j] - m;
        s2 += d * d;
    }
    mu[j]   = m;
    istd[j] = rsqrtf(s2 * (1.f / (float)BS) + BN_EPS);
}

// ---------------------------------------------------------------------------
// K4: out = relu(gamma*(y-mu)*istd + beta), then L2-normalize each row.
// One block per row.
// ---------------------------------------------------------------------------
__global__ __launch_bounds__(256) void k4_norm(const float* __restrict__ y,
                                               const float* __restrict__ mu,
                                               const float* __restrict__ istd,
                                               const float* __restrict__ gamma,
                                               const float* __restrict__ beta,
                                               float* __restrict__ out) {
    const int n   = blockIdx.x;
    const int tid = threadIdx.x;

    float o[4];
    float ss = 0.f;
#pragma unroll
    for (int m = 0; m < 4; ++m) {
        const int j = tid + 256 * m;
        float v = (y[(size_t)n * D_DIM + j] - mu[j]) * istd[j] * gamma[j] + beta[j];
        v = fmaxf(v, 0.f);
        o[m] = v;
        ss += v * v;
    }

#pragma unroll
    for (int off = 32; off > 0; off >>= 1) ss += __shfl_down(ss, off, 64);
    __shared__ float sred[4];
    __shared__ float stot;
    if ((tid & 63) == 0) sred[tid >> 6] = ss;
    __syncthreads();
    if (tid == 0) stot = sred[0] + sred[1] + sred[2] + sred[3];
    __syncthreads();

    const float scale = 1.f / fmaxf(sqrtf(stot), L2_EPS);
#pragma unroll
    for (int m = 0; m < 4; ++m) {
        out[(size_t)n * D_DIM + tid + 256 * m] = o[m] * scale;
    }
}

extern "C" void kernel_launch(void* const* d_in, const int* in_sizes, int n_in,
                              void* d_out, int out_size, void* d_ws, size_t ws_size,
                              hipStream_t stream) {
    const float* x     = (const float*)d_in[0];
    const float* W     = (const float*)d_in[1];
    const float* bvec  = (const float*)d_in[2];
    const float* gamma = (const float*)d_in[3];
    const float* beta  = (const float*)d_in[4];

    float* q    = (float*)d_ws;                 // 80*1024 floats
    float* y    = q + BS * D_DIM;               // 80*1024 floats
    float* mu   = y + BS * D_DIM;               // 1024 floats
    float* istd = mu + D_DIM;                   // 1024 floats

    float* out = (float*)d_out;

    k1_q   <<<BS,                 256, 0, stream>>>(x, q);
    k2_gemm<<<BS * D_DIM / 256,   256, 0, stream>>>(q, W, bvec, y);
    k3_stats<<<D_DIM / 256,       256, 0, stream>>>(y, mu, istd);
    k4_norm<<<BS,                 256, 0, stream>>>(y, mu, istd, gamma, beta, out);
}

// Round 2
// 80.465 us; speedup vs baseline: 1.8687x; 1.8687x over previous
//
#include <hip/hip_runtime.h>
#include <hip/hip_bf16.h>
#include <math.h>

#define D_DIM   1024
#define BS      80      // B * STEP
#define BATCH   16
#define STEPS   5
#define ALPHA   0.01f
#define BN_EPS  1e-5f
#define L2_EPS  1e-12f

#define K2_NN   8       // n's per wave in k2
#define K2_NG   (BS / K2_NN)   // 10 n-groups

// ---------------------------------------------------------------------------
// K1: closed-form fast-weight readout.
//   q[n,i] = ALPHA * sum_{s=0..t} c_s * x_k[s][i] * prod_{r=s+1..t}(1 - ALPHA*x_k[r][i]^2)
// t = n>>4 (step), bb = n&15 (batch); keys x[bb*5+s], query v = x[n],
// c_s = dot(key_s, v).  One block per row; one float4 per thread (exact fit).
// Also zeroes the BN column-sum buffers (blocks 0..7) for K2's atomics.
// ---------------------------------------------------------------------------
__global__ __launch_bounds__(256) void k1_q(const float* __restrict__ x,
                                            float* __restrict__ q,
                                            float* __restrict__ colsum,
                                            float* __restrict__ colsumsq) {
    const int n    = blockIdx.x;
    const int tid  = threadIdx.x;
    const int lane = tid & 63;
    const int wid  = tid >> 6;
    const int t    = n >> 4;
    const int bb   = n & 15;

    if (n < 8) {                       // zero 2*1024 floats of stats buffers
        colsum  [n * 256 + tid] = 0.f; // n in 0..3 -> colsum, 4..7 -> colsumsq
    } else if (n < 16) {
        colsumsq[(n - 8) * 256 + tid] = 0.f;
    }
    // (n<4 covers colsum fully when 8 blocks * 256 = 2048; split as above)

    const float4* __restrict__ xv = (const float4*)(x + (size_t)n * D_DIM);
    const float4 v = xv[tid];

    float4 k[STEPS];
#pragma unroll
    for (int s = 0; s < STEPS; ++s)
        k[s] = ((const float4*)(x + (size_t)(bb * STEPS + s) * D_DIM))[tid];

    float p[STEPS];
#pragma unroll
    for (int s = 0; s < STEPS; ++s)
        p[s] = k[s].x * v.x + k[s].y * v.y + k[s].z * v.z + k[s].w * v.w;

#pragma unroll
    for (int off = 32; off; off >>= 1) {
#pragma unroll
        for (int s = 0; s < STEPS; ++s) p[s] += __shfl_xor(p[s], off, 64);
    }

    __shared__ float sh[4][STEPS];
    if (lane == 0) {
#pragma unroll
        for (int s = 0; s < STEPS; ++s) sh[wid][s] = p[s];
    }
    __syncthreads();
    float c[STEPS];
#pragma unroll
    for (int s = 0; s < STEPS; ++s)
        c[s] = sh[0][s] + sh[1][s] + sh[2][s] + sh[3][s];

    float4 acc = make_float4(0.f, 0.f, 0.f, 0.f);
    for (int s = 0; s <= t; ++s) {
        const float4 xs = k[s];
        acc.x = acc.x * (1.f - ALPHA * xs.x * xs.x) + c[s] * xs.x;
        acc.y = acc.y * (1.f - ALPHA * xs.y * xs.y) + c[s] * xs.y;
        acc.z = acc.z * (1.f - ALPHA * xs.z * xs.z) + c[s] * xs.z;
        acc.w = acc.w * (1.f - ALPHA * xs.w * xs.w) + c[s] * xs.w;
    }
    acc.x *= ALPHA; acc.y *= ALPHA; acc.z *= ALPHA; acc.w *= ALPHA;
    ((float4*)(q + (size_t)n * D_DIM))[tid] = acc;
}

// ---------------------------------------------------------------------------
// K2: y = q @ W^T + b, fused BN column statistics (atomic sum / sumsq).
// One wave per (4 consecutive j, 8 n). Lanes index K: all W/q loads are
// fully coalesced float4 (1 KiB / instruction). Each wave holds 4 W rows in
// registers (64 VGPRs) and reuses every q load 4x. Butterfly reduce, lane 0
// writes y as float4 and accumulates column sums locally, 8 atomics per wave.
// Grid: 640 blocks x 256 = 2560 waves = 10 waves/CU.
// ---------------------------------------------------------------------------
__global__ __launch_bounds__(256) void k2_gemm(const float* __restrict__ q,
                                               const float* __restrict__ W,
                                               const float* __restrict__ bvec,
                                               float* __restrict__ y,
                                               float* __restrict__ colsum,
                                               float* __restrict__ colsumsq) {
    const int tid  = threadIdx.x;
    const int lane = tid & 63;
    const int wid  = tid >> 6;
    const int wave = blockIdx.x * 4 + wid;   // 0..2559
    const int jg   = wave & 255;             // j-group: j0 = jg*4
    const int ng   = wave >> 8;              // 0..9
    const int j0   = jg * 4;
    const int n0   = ng * K2_NN;

    const float4* __restrict__ W4 = (const float4*)W;
    const float4* __restrict__ q4 = (const float4*)q;

    float4 w[4][4];
#pragma unroll
    for (int jj = 0; jj < 4; ++jj)
#pragma unroll
        for (int m = 0; m < 4; ++m)
            w[jj][m] = W4[(size_t)(j0 + jj) * 256 + lane + 64 * m];

    const float4 b4 = ((const float4*)bvec)[jg];

    float csum[4] = {0.f, 0.f, 0.f, 0.f};
    float csq [4] = {0.f, 0.f, 0.f, 0.f};

#pragma unroll 2
    for (int nn = 0; nn < K2_NN; ++nn) {
        const int n = n0 + nn;
        float4 qv[4];
#pragma unroll
        for (int m = 0; m < 4; ++m)
            qv[m] = q4[(size_t)n * 256 + lane + 64 * m];

        float s[4] = {0.f, 0.f, 0.f, 0.f};
#pragma unroll
        for (int jj = 0; jj < 4; ++jj) {
#pragma unroll
            for (int m = 0; m < 4; ++m) {
                s[jj] += w[jj][m].x * qv[m].x + w[jj][m].y * qv[m].y
                       + w[jj][m].z * qv[m].z + w[jj][m].w * qv[m].w;
            }
        }
#pragma unroll
        for (int off = 32; off; off >>= 1) {
#pragma unroll
            for (int jj = 0; jj < 4; ++jj) s[jj] += __shfl_xor(s[jj], off, 64);
        }
        if (lane == 0) {
            float4 yv = make_float4(s[0] + b4.x, s[1] + b4.y,
                                    s[2] + b4.z, s[3] + b4.w);
            ((float4*)y)[(size_t)n * 256 + jg] = yv;
            csum[0] += yv.x; csum[1] += yv.y; csum[2] += yv.z; csum[3] += yv.w;
            csq[0] += yv.x * yv.x; csq[1] += yv.y * yv.y;
            csq[2] += yv.z * yv.z; csq[3] += yv.w * yv.w;
        }
    }
    if (lane == 0) {
#pragma unroll
        for (int jj = 0; jj < 4; ++jj) {
            atomicAdd(&colsum [j0 + jj], csum[jj]);
            atomicAdd(&colsumsq[j0 + jj], csq[jj]);
        }
    }
}

// ---------------------------------------------------------------------------
// K4: BN (stats from colsum/colsumsq) + ReLU + row L2-normalize.
// One block per row; mu/istd recomputed inline per column (L2-hot, cheap).
// ---------------------------------------------------------------------------
__global__ __launch_bounds__(256) void k4_norm(const float* __restrict__ y,
                                               const float* __restrict__ colsum,
                                               const float* __restrict__ colsumsq,
                                               const float* __restrict__ gamma,
                                               const float* __restrict__ beta,
                                               float* __restrict__ out) {
    const int n   = blockIdx.x;
    const int tid = threadIdx.x;

    const float inv_bs = 1.f / (float)BS;

    float o[4];
    float ss = 0.f;
#pragma unroll
    for (int m = 0; m < 4; ++m) {
        const int j = tid + 256 * m;
        const float mu   = colsum[j] * inv_bs;
        const float var  = colsumsq[j] * inv_bs - mu * mu;
        const float istd = rsqrtf(var + BN_EPS);
        float v = (y[(size_t)n * D_DIM + j] - mu) * istd * gamma[j] + beta[j];
        v = fmaxf(v, 0.f);
        o[m] = v;
        ss += v * v;
    }

#pragma unroll
    for (int off = 32; off; off >>= 1) ss += __shfl_xor(ss, off, 64);
    __shared__ float sred[4];
    if ((tid & 63) == 0) sred[tid >> 6] = ss;
    __syncthreads();
    const float stot = sred[0] + sred[1] + sred[2] + sred[3];

    const float scale = 1.f / fmaxf(sqrtf(stot), L2_EPS);
#pragma unroll
    for (int m = 0; m < 4; ++m)
        out[(size_t)n * D_DIM + tid + 256 * m] = o[m] * scale;
}

extern "C" void kernel_launch(void* const* d_in, const int* in_sizes, int n_in,
                              void* d_out, int out_size, void* d_ws, size_t ws_size,
                              hipStream_t stream) {
    const float* x     = (const float*)d_in[0];
    const float* W     = (const float*)d_in[1];
    const float* bvec  = (const float*)d_in[2];
    const float* gamma = (const float*)d_in[3];
    const float* beta  = (const float*)d_in[4];

    float* q        = (float*)d_ws;            // 80*1024
    float* y        = q + BS * D_DIM;          // 80*1024
    float* colsum   = y + BS * D_DIM;          // 1024
    float* colsumsq = colsum + D_DIM;          // 1024

    float* out = (float*)d_out;

    k1_q   <<<BS,                    256, 0, stream>>>(x, q, colsum, colsumsq);
    k2_gemm<<<(256 * K2_NG) / 4,     256, 0, stream>>>(q, W, bvec, y, colsum, colsumsq);
    k4_norm<<<BS,                    256, 0, stream>>>(y, colsum, colsumsq, gamma, beta, out);
}